// Round 9
// baseline (140.809 us; speedup 1.0000x reference)
//
#include <hip/hip_runtime.h>

#define E 1024
#define HH 64
#define BB 4
#define SS 2048
#define BS (BB*SS)   // 8192 rows
#define NSLOT 144    // per-batch split-K slots: sum_{qt=0}^{31} (qt/4 + 1)

typedef unsigned short u16;
typedef short bf16x8 __attribute__((ext_vector_type(8)));
typedef float f32x4 __attribute__((ext_vector_type(4)));

#define LOG2E_O8 0.18033688011112042f   // log2(e)/8 : folds 1/sqrt(64) + exp2 domain

__device__ inline u16 f2bf(float f) {
    unsigned int u = __float_as_uint(f);
    unsigned int r = (u + 0x7FFFu + ((u >> 16) & 1u)) >> 16;   // RNE
    return (u16)r;
}
__device__ inline float bf2f(u16 h) {
    return __uint_as_float(((unsigned int)h) << 16);
}

// ---------- Kernel 1: fused LayerNorm (blocks 0..2047) + W cast (blocks 2048..2239) ----------
__global__ __launch_bounds__(256) void ln_wcast(const float* __restrict__ x,
        const float* __restrict__ gamma, const float* __restrict__ beta,
        const float* __restrict__ Wq, const float* __restrict__ Wk,
        const float* __restrict__ Wv,
        u16* __restrict__ xn, u16* __restrict__ wc) {
    const int t = threadIdx.x;
    if (blockIdx.x < 2048) {
        // ---- LayerNorm: wave-per-row, fp32 -> bf16 (gamma/beta applied here) ----
        const int w = t >> 6, lane = t & 63;
        const size_t row = (size_t)blockIdx.x * 4 + w;
        const float4* xr = (const float4*)(x + row * E);
        float4 v[4];
        #pragma unroll
        for (int i = 0; i < 4; ++i) v[i] = xr[lane + 64 * i];
        float s = 0.f, sq = 0.f;
        #pragma unroll
        for (int i = 0; i < 4; ++i) {
            s  += v[i].x + v[i].y + v[i].z + v[i].w;
            sq += v[i].x*v[i].x + v[i].y*v[i].y + v[i].z*v[i].z + v[i].w*v[i].w;
        }
        #pragma unroll
        for (int off = 32; off > 0; off >>= 1) {
            s  += __shfl_xor(s,  off);
            sq += __shfl_xor(sq, off);
        }
        const float mean = s * (1.0f / E);
        const float var  = sq * (1.0f / E) - mean * mean;
        const float rstd = rsqrtf(var + 1e-5f);
        const float4* gr = (const float4*)gamma;
        const float4* br = (const float4*)beta;
        #pragma unroll
        for (int i = 0; i < 4; ++i) {
            const float4 g  = gr[lane + 64 * i];
            const float4 bt = br[lane + 64 * i];
            ushort4 o;
            o.x = f2bf((v[i].x - mean) * rstd * g.x + bt.x);
            o.y = f2bf((v[i].y - mean) * rstd * g.y + bt.y);
            o.z = f2bf((v[i].z - mean) * rstd * g.z + bt.z);
            o.w = f2bf((v[i].w - mean) * rstd * g.w + bt.w);
            *(ushort4*)(xn + row * E + (lane + 64 * i) * 4) = o;
        }
    } else {
        // ---- W cast -> bf16 (Wq rows pre-scaled by log2(e)/8) ----
        const int row = blockIdx.x - 2048;   // 0..191
        const float* src = (row < 64)  ? (Wq + (size_t)row * E)
                         : (row < 128) ? (Wk + (size_t)(row - 64) * E)
                                       : (Wv + (size_t)(row - 128) * E);
        const float sc = (row < 64) ? LOG2E_O8 : 1.0f;
        const float4 v = *(const float4*)(src + t * 4);
        ushort4 o;
        o.x = f2bf(v.x * sc); o.y = f2bf(v.y * sc);
        o.z = f2bf(v.z * sc); o.w = f2bf(v.w * sc);
        *(ushort4*)(wc + (size_t)row * E + t * 4) = o;
    }
}

// ---------- Kernel 2: QKV projection, MFMA bf16, 32x96 blocks, 128-k chunks ----------
// R9: TLP fix. LDS cut 64->40 KB (W SINGLE-buffered, X double-buffered) -> 4 blocks/CU
// = 16 waves/CU (was 2 blocks/8 waves: R5 showed the front end is latency-bound and
// scales with occupancy). W's next chunk is issued to REGISTERS before compute (T14
// issue-early / write-late) so the single-buffer's 2-barrier handoff exposes only the
// ds_write, not the global-load latency. V written pre-transposed: vt[b][h][key]
__global__ __launch_bounds__(256, 4) void qkv_mfma(const u16* __restrict__ xn,
        const u16* __restrict__ wc,
        u16* __restrict__ qb, u16* __restrict__ kb, u16* __restrict__ vt) {
    const int mb   = blockIdx.x >> 1;
    const int half = blockIdx.x & 1;
    const int row0 = mb * 32;
    const int t = threadIdx.x;
    const int w = t >> 6, lane = t & 63;
    const int quad = lane >> 4, r15 = lane & 15;
    const int mt = w >> 1, cgrp = w & 1;
    __shared__ u16 Xs[2][32 * 128];   // 16 KB (double-buffered)
    __shared__ u16 Ws[96 * 128];      // 24 KB (single-buffered)
    f32x4 acc[3] = {};
    const int xrow = mt * 16 + r15;

    // staging identities (constant per thread)
    const int sx_row = t >> 3, sx_ch = t & 7;
    // W: idx=i*256+t -> wl=idx>>4, u16slot=(idx&15): hf=slot>>3, ch=slot&7
    const int sw_wl0 = t >> 4, sw_u = t & 15;
    const int sw_hf = sw_u >> 3, sw_ch = sw_u & 7;

    // ---- prologue: stage chunk 0 (X -> Xs[0], W -> Ws, both direct) ----
    {
        #pragma unroll
        for (int hf = 0; hf < 2; ++hf) {
            const uint4 d = *(const uint4*)(xn + (size_t)(row0 + sx_row) * E
                                            + hf * 64 + sx_ch * 8);
            *(uint4*)&Xs[0][sx_row * 128 + hf * 64 + (sx_ch ^ (sx_row & 7)) * 8] = d;
        }
        #pragma unroll
        for (int i = 0; i < 6; ++i) {
            const int wl = i * 16 + sw_wl0;
            const uint4 d = *(const uint4*)(wc + (size_t)(half * 96 + wl) * E
                                            + sw_hf * 64 + sw_ch * 8);
            *(uint4*)&Ws[wl * 128 + sw_hf * 64 + (sw_ch ^ (wl & 7)) * 8] = d;
        }
    }
    __syncthreads();

    for (int kc8 = 0; kc8 < 8; ++kc8) {
        const int cur = kc8 & 1;
        uint4 wreg[6];
        if (kc8 < 7) {
            const int kn = kc8 + 1;
            // X next -> idle dbuf slot (direct; nobody reads Xs[cur^1] this iteration)
            #pragma unroll
            for (int hf = 0; hf < 2; ++hf) {
                const uint4 d = *(const uint4*)(xn + (size_t)(row0 + sx_row) * E
                                                + kn * 128 + hf * 64 + sx_ch * 8);
                *(uint4*)&Xs[cur ^ 1][sx_row * 128 + hf * 64 + (sx_ch ^ (sx_row & 7)) * 8] = d;
            }
            // W next -> registers (loads fly during the MFMA phase below)
            #pragma unroll
            for (int i = 0; i < 6; ++i) {
                const int wl = i * 16 + sw_wl0;
                wreg[i] = *(const uint4*)(wc + (size_t)(half * 96 + wl) * E
                                          + kn * 128 + sw_hf * 64 + sw_ch * 8);
            }
        }
        // ---- compute on Xs[cur] and Ws ----
        #pragma unroll
        for (int kk = 0; kk < 4; ++kk) {
            const int hf = kk >> 1, q4 = (kk & 1) * 4 + quad;
            const bf16x8 af = *(const bf16x8*)&Xs[cur][xrow * 128 + hf * 64 + (q4 ^ (xrow & 7)) * 8];
            #pragma unroll
            for (int j = 0; j < 3; ++j) {
                const int wl = (cgrp * 3 + j) * 16 + r15;
                const bf16x8 bfr = *(const bf16x8*)&Ws[wl * 128 + hf * 64 + (q4 ^ (wl & 7)) * 8];
                acc[j] = __builtin_amdgcn_mfma_f32_16x16x32_bf16(af, bfr, acc[j], 0, 0, 0);
            }
        }
        __syncthreads();   // all waves done READING Ws (and X-next writes done)
        if (kc8 < 7) {
            #pragma unroll
            for (int i = 0; i < 6; ++i) {
                const int wl = i * 16 + sw_wl0;
                *(uint4*)&Ws[wl * 128 + sw_hf * 64 + (sw_ch ^ (wl & 7)) * 8] = wreg[i];
            }
        }
        __syncthreads();   // Ws refilled, visible to all
    }

    const int b    = row0 >> 11;
    const int key0 = row0 & 2047;
    #pragma unroll
    for (int j = 0; j < 3; ++j) {
        const int cg  = half * 96 + cgrp * 48 + j * 16 + r15;
        const int sel = cg >> 6;
        const int col = cg & 63;
        if (sel < 2) {
            u16* base = (sel == 0) ? qb : kb;
            #pragma unroll
            for (int r = 0; r < 4; ++r) {
                const size_t row = (size_t)row0 + mt * 16 + quad * 4 + r;
                base[row * HH + col] = f2bf(acc[j][r]);
            }
        } else {
            ushort4 pk;
            pk.x = f2bf(acc[j][0]); pk.y = f2bf(acc[j][1]);
            pk.z = f2bf(acc[j][2]); pk.w = f2bf(acc[j][3]);
            *(ushort4*)(vt + (size_t)b * HH * SS + (size_t)col * SS
                           + key0 + mt * 16 + quad * 4) = pk;
        }
    }
}

// ---------- Kernel 3: split-K causal flash attention — PAIRED query tiles, HEAVY-FIRST ----------
// Block = (b, a-group, rp: tile pair, c: 256-key chunk). The flat pair-slot is
// REVERSED (s2 = 71 - raw) so a=7 blocks (4 tiles staged, 8 q-strips = ~4x the work
// of a=0) dispatch FIRST; the light direct-write blocks fill the tail.
__global__ __launch_bounds__(256) void attn_partial(const u16* __restrict__ qb,
        const u16* __restrict__ kb, const u16* __restrict__ vt,
        u16* __restrict__ po, float* __restrict__ pl,
        float* __restrict__ out) {
    const int bid = blockIdx.x;                 // BB * 72
    const int b   = bid / 72;
    const int s2  = 71 - (bid - b * 72);        // heavy-first: reverse pair-slot order
    int a = (int)((sqrtf(4.0f * s2 + 1.0f) - 1.0f) * 0.5f);
    while ((a + 1) * (a + 2) <= s2) ++a;        // fixup (fp edge safety)
    while (a * (a + 1) > s2) --a;
    const int rem = s2 - a * (a + 1);
    const int rp  = rem / (a + 1);
    const int c   = rem - rp * (a + 1);
    const int qt0 = 4 * a + 2 * rp;             // pair (qt0, qt0+1)
    const int nc  = a + 1;
    const int t = threadIdx.x;
    const int w = t >> 6, lane = t & 63;
    const int quad = lane >> 4, r15 = lane & 15;

    __shared__ u16 Ks[4 * 64 * 64];   // 32 KB: [tile][key][h], XOR-swizzled chunks
    __shared__ u16 VT[4 * 64 * 64];   // 32 KB: [tile][h][key], XOR-swizzled chunks
    __shared__ u16 Ps[64 * 64];       // 8 KB:  [qrow][key], per-wave strips (reused per qi)

    // Q A-frags for both tiles of the pair
    bf16x8 qf0[2], qf1[2];
    #pragma unroll
    for (int qi = 0; qi < 2; ++qi) {
        const size_t qrow = ((size_t)b * SS + (qt0 + qi) * 64 + w * 16 + r15) * HH;
        qf0[qi] = *(const bf16x8*)(qb + qrow + quad * 8);
        qf1[qi] = *(const bf16x8*)(qb + qrow + 32 + quad * 8);
    }

    // tiles to stage: all 4 for interior chunks; 2rp+2 for the diagonal chunk (c==a)
    const int ntmax = (c < a) ? 4 : (2 * rp + 2);

    {   // ---- stage ALL needed tiles in one burst ----
        const int row = t >> 2, ch0 = (t & 3) * 2;
        for (int tl = 0; tl < ntmax; ++tl) {
            const int kt = (c * 4 + tl) << 6;
            const uint4* srcK = (const uint4*)(kb + ((size_t)b * SS + kt + row) * HH + ch0 * 8);
            const uint4 k0 = srcK[0], k1 = srcK[1];
            *(uint4*)&Ks[tl * 4096 + row * 64 + ((ch0    ) ^ (row & 7)) * 8] = k0;
            *(uint4*)&Ks[tl * 4096 + row * 64 + ((ch0 + 1) ^ (row & 7)) * 8] = k1;
            const uint4* srcV = (const uint4*)(vt + (size_t)b * HH * SS + (size_t)row * SS
                                               + kt + ch0 * 8);
            const uint4 v0 = srcV[0], v1 = srcV[1];
            *(uint4*)&VT[tl * 4096 + row * 64 + ((ch0    ) ^ (row & 7)) * 8] = v0;
            *(uint4*)&VT[tl * 4096 + row * 64 + ((ch0 + 1) ^ (row & 7)) * 8] = v1;
        }
    }
    __syncthreads();   // the ONLY block-wide barrier

    f32x4 o[2][4] = {};
    float l_[2][4] = {};

    for (int tl = 0; tl < ntmax; ++tl) {
        const int tile = c * 4 + tl;
        const u16* KsT = &Ks[tl * 4096];
        const u16* VTT = &VT[tl * 4096];

        // K/V fragments: loaded ONCE per tile, reused by both q-strips
        bf16x8 kf0[4], kf1[4], vf0[4], vf1[4];
        #pragma unroll
        for (int nt = 0; nt < 4; ++nt) {
            const int krow = nt * 16 + r15;
            kf0[nt] = *(const bf16x8*)&KsT[krow * 64 + ((    quad) ^ (krow & 7)) * 8];
            kf1[nt] = *(const bf16x8*)&KsT[krow * 64 + ((4 + quad) ^ (krow & 7)) * 8];
            vf0[nt] = *(const bf16x8*)&VTT[krow * 64 + ((    quad) ^ (krow & 7)) * 8];
            vf1[nt] = *(const bf16x8*)&VTT[krow * 64 + ((4 + quad) ^ (krow & 7)) * 8];
        }

        #pragma unroll
        for (int qi = 0; qi < 2; ++qi) {
            const int qt_i = qt0 + qi;
            if (tile > qt_i) continue;       // only fires: c==a, qi==0, tl==2rp+1

            // S strip = Q K^T (16 x 64)
            f32x4 s4[4] = {};
            #pragma unroll
            for (int nt = 0; nt < 4; ++nt) {
                s4[nt] = __builtin_amdgcn_mfma_f32_16x16x32_bf16(qf0[qi], kf0[nt], s4[nt], 0, 0, 0);
                s4[nt] = __builtin_amdgcn_mfma_f32_16x16x32_bf16(qf1[qi], kf1[nt], s4[nt], 0, 0, 0);
            }
            if (tile == qt_i) {   // diagonal tile: mask key > query
                #pragma unroll
                for (int nt = 0; nt < 4; ++nt)
                    #pragma unroll
                    for (int r = 0; r < 4; ++r)
                        if (nt * 16 + r15 > w * 16 + quad * 4 + r) s4[nt][r] = -INFINITY;
            }

            // un-shifted softmax: p = exp2(s). Row sums deferred (per-lane).
            float p[4][4];
            #pragma unroll
            for (int r = 0; r < 4; ++r) {
                #pragma unroll
                for (int nt = 0; nt < 4; ++nt)
                    p[nt][r] = __builtin_amdgcn_exp2f(s4[nt][r]);
                l_[qi][r] += (p[0][r] + p[1][r]) + (p[2][r] + p[3][r]);
            }

            // P strip -> LDS (per-wave strip, reused across qi; in-wave ordering)
            #pragma unroll
            for (int nt = 0; nt < 4; ++nt)
                #pragma unroll
                for (int r = 0; r < 4; ++r) {
                    const int prow = w * 16 + quad * 4 + r;
                    const int col  = nt * 16 + r15;
                    Ps[prow * 64 + (((col >> 3) ^ (prow & 7)) * 8) + (col & 7)] = f2bf(p[nt][r]);
                }
            const int arow = w * 16 + r15;
            const bf16x8 pf0 = *(const bf16x8*)&Ps[arow * 64 + ((    quad) ^ (arow & 7)) * 8];
            const bf16x8 pf1 = *(const bf16x8*)&Ps[arow * 64 + ((4 + quad) ^ (arow & 7)) * 8];

            // O strip += P V
            #pragma unroll
            for (int ht = 0; ht < 4; ++ht) {
                o[qi][ht] = __builtin_amdgcn_mfma_f32_16x16x32_bf16(pf0, vf0[ht], o[qi][ht], 0, 0, 0);
                o[qi][ht] = __builtin_amdgcn_mfma_f32_16x16x32_bf16(pf1, vf1[ht], o[qi][ht], 0, 0, 0);
            }
        }
    }

    // one row-sum reduction per block per tile-pair
    #pragma unroll
    for (int qi = 0; qi < 2; ++qi)
        #pragma unroll
        for (int r = 0; r < 4; ++r) {
            l_[qi][r] += __shfl_xor(l_[qi][r], 1); l_[qi][r] += __shfl_xor(l_[qi][r], 2);
            l_[qi][r] += __shfl_xor(l_[qi][r], 4); l_[qi][r] += __shfl_xor(l_[qi][r], 8);
        }

    #pragma unroll
    for (int qi = 0; qi < 2; ++qi) {
        const int qt_i = qt0 + qi;
        if (nc == 1) {   // a==0: pair saw all keys -> write out directly
            #pragma unroll
            for (int r = 0; r < 4; ++r) {
                const float inv = 1.0f / l_[qi][r];
                const size_t orow = ((size_t)b * SS + qt_i * 64 + w * 16 + quad * 4 + r) * HH;
                #pragma unroll
                for (int ht = 0; ht < 4; ++ht)
                    out[orow + ht * 16 + r15] = o[qi][ht][r] * inv;
            }
        } else {
            const int slot = b * NSLOT + 2 * a * (a + 1) + (2 * rp + qi) * (a + 1) + c;
            #pragma unroll
            for (int r = 0; r < 4; ++r) {
                const int q = w * 16 + quad * 4 + r;
                #pragma unroll
                for (int ht = 0; ht < 4; ++ht)
                    po[(size_t)slot * 4096 + q * 64 + ht * 16 + r15] = f2bf(o[qi][ht][r]);
                if (r15 == 0) pl[slot * 64 + q] = l_[qi][r];
            }
        }
    }
}

// ---------- Kernel 4: split-K reduce — plain sums (po is bf16), qt>=4 only, HEAVY-FIRST ----------
__global__ __launch_bounds__(256) void attn_reduce(const u16* __restrict__ po,
        const float* __restrict__ pl, float* __restrict__ out) {
    const int bid = blockIdx.x;            // BB*28*4 = 448 (qt 4..31 only)
    const int b = bid / 112, rem = bid - b * 112;
    const int qt = 31 - (rem >> 2);        // heavy-first: qt=31 (nc=8) dispatched first
    const int qq = rem & 3;
    const int a = qt >> 2, r_ = qt & 3;
    const int nc = a + 1;
    const int sbase = b * NSLOT + 2 * a * (a + 1) + r_ * (a + 1);
    const int t = threadIdx.x;
    const int h = t & 63, qr = t >> 6;
    #pragma unroll
    for (int i = 0; i < 4; ++i) {
        const int q = qq * 16 + qr * 4 + i;   // query within 64-tile
        float osum = 0.f, lsum = 0.f;
        // fixed-trip predicated unroll (nc is block-uniform, 2..8): ILP on the chunk loads
        #pragma unroll
        for (int cidx = 0; cidx < 8; ++cidx) {
            if (cidx < nc) {
                osum += bf2f(po[(size_t)(sbase + cidx) * 4096 + q * 64 + h]);
                lsum += pl[(sbase + cidx) * 64 + q];
            }
        }
        out[((size_t)b * SS + (qt << 6) + q) * HH + h] = osum / lsum;
    }
}

// ---------- launch ----------
extern "C" void kernel_launch(void* const* d_in, const int* in_sizes, int n_in,
                              void* d_out, int out_size, void* d_ws, size_t ws_size,
                              hipStream_t stream) {
    const float* x     = (const float*)d_in[0];
    const float* gamma = (const float*)d_in[1];
    const float* beta  = (const float*)d_in[2];
    const float* Wq    = (const float*)d_in[3];
    const float* Wk    = (const float*)d_in[4];
    const float* Wv    = (const float*)d_in[5];
    float* out = (float*)d_out;

    // ws layout: xn 16.78MB | wc 384KB | qb/kb/vt 1MB each | po 4.72MB (bf16) | pl 144KB
    char* p = (char*)d_ws;
    u16*   xn   = (u16*)p;                         p += (size_t)BS * E * 2;
    u16*   wc   = (u16*)p;                         p += 393216;
    u16*   qb   = (u16*)p;                         p += (size_t)BS * HH * 2;
    u16*   kb   = (u16*)p;                         p += (size_t)BS * HH * 2;
    u16*   vt   = (u16*)p;                         p += (size_t)BS * HH * 2;
    u16*   po   = (u16*)p;                         p += (size_t)BB * NSLOT * 4096 * 2;
    float* pl   = (float*)p;

    ln_wcast    <<<2048 + 192,  256, 0, stream>>>(x, gamma, beta, Wq, Wk, Wv, xn, wc);
    qkv_mfma    <<<BS / 16,     256, 0, stream>>>(xn, wc, qb, kb, vt);
    attn_partial<<<BB * 72,     256, 0, stream>>>(qb, kb, vt, po, pl, out);
    attn_reduce <<<BB * 112,    256, 0, stream>>>(po, pl, out);
}

// Round 10
// 117.598 us; speedup vs baseline: 1.1974x; 1.1974x over previous
//
#include <hip/hip_runtime.h>

#define E 1024
#define HH 64
#define BB 4
#define SS 2048
#define BS (BB*SS)   // 8192 rows
#define NSLOT 144    // per-batch split-K slots: sum_{qt=0}^{31} (qt/4 + 1)

typedef unsigned short u16;
typedef short bf16x8 __attribute__((ext_vector_type(8)));
typedef float f32x4 __attribute__((ext_vector_type(4)));

#define LOG2E_O8 0.18033688011112042f   // log2(e)/8 : folds 1/sqrt(64) + exp2 domain

__device__ inline u16 f2bf(float f) {
    unsigned int u = __float_as_uint(f);
    unsigned int r = (u + 0x7FFFu + ((u >> 16) & 1u)) >> 16;   // RNE
    return (u16)r;
}
__device__ inline float bf2f(u16 h) {
    return __uint_as_float(((unsigned int)h) << 16);
}

// ---------- Kernel 1: fused LayerNorm (blocks 0..2047) + W cast (blocks 2048..2239) ----------
__global__ __launch_bounds__(256) void ln_wcast(const float* __restrict__ x,
        const float* __restrict__ gamma, const float* __restrict__ beta,
        const float* __restrict__ Wq, const float* __restrict__ Wk,
        const float* __restrict__ Wv,
        u16* __restrict__ xn, u16* __restrict__ wc) {
    const int t = threadIdx.x;
    if (blockIdx.x < 2048) {
        // ---- LayerNorm: wave-per-row, fp32 -> bf16 (gamma/beta applied here) ----
        const int w = t >> 6, lane = t & 63;
        const size_t row = (size_t)blockIdx.x * 4 + w;
        const float4* xr = (const float4*)(x + row * E);
        float4 v[4];
        #pragma unroll
        for (int i = 0; i < 4; ++i) v[i] = xr[lane + 64 * i];
        float s = 0.f, sq = 0.f;
        #pragma unroll
        for (int i = 0; i < 4; ++i) {
            s  += v[i].x + v[i].y + v[i].z + v[i].w;
            sq += v[i].x*v[i].x + v[i].y*v[i].y + v[i].z*v[i].z + v[i].w*v[i].w;
        }
        #pragma unroll
        for (int off = 32; off > 0; off >>= 1) {
            s  += __shfl_xor(s,  off);
            sq += __shfl_xor(sq, off);
        }
        const float mean = s * (1.0f / E);
        const float var  = sq * (1.0f / E) - mean * mean;
        const float rstd = rsqrtf(var + 1e-5f);
        const float4* gr = (const float4*)gamma;
        const float4* br = (const float4*)beta;
        #pragma unroll
        for (int i = 0; i < 4; ++i) {
            const float4 g  = gr[lane + 64 * i];
            const float4 bt = br[lane + 64 * i];
            ushort4 o;
            o.x = f2bf((v[i].x - mean) * rstd * g.x + bt.x);
            o.y = f2bf((v[i].y - mean) * rstd * g.y + bt.y);
            o.z = f2bf((v[i].z - mean) * rstd * g.z + bt.z);
            o.w = f2bf((v[i].w - mean) * rstd * g.w + bt.w);
            *(ushort4*)(xn + row * E + (lane + 64 * i) * 4) = o;
        }
    } else {
        // ---- W cast -> bf16 (Wq rows pre-scaled by log2(e)/8) ----
        const int row = blockIdx.x - 2048;   // 0..191
        const float* src = (row < 64)  ? (Wq + (size_t)row * E)
                         : (row < 128) ? (Wk + (size_t)(row - 64) * E)
                                       : (Wv + (size_t)(row - 128) * E);
        const float sc = (row < 64) ? LOG2E_O8 : 1.0f;
        const float4 v = *(const float4*)(src + t * 4);
        ushort4 o;
        o.x = f2bf(v.x * sc); o.y = f2bf(v.y * sc);
        o.z = f2bf(v.z * sc); o.w = f2bf(v.w * sc);
        *(ushort4*)(wc + (size_t)row * E + t * 4) = o;
    }
}

// ---------- Kernel 2: QKV projection, MFMA bf16, 32x96 blocks, 128-k chunks ----------
// Double-buffered LDS K-loop (stage k+1 before compute k, ONE barrier per iteration).
// V written pre-transposed: vt[b][h][key]
// NOTE (R9 lesson): do NOT single-buffer W for occupancy — 2 barriers/iter + 24 VGPR
// of in-flight W regs under launch_bounds(256,4) regressed 118->141. This 2-block/CU
// shape is the verified optimum of 5 staging variants (R2/R6/R9 all <= neutral).
__global__ __launch_bounds__(256) void qkv_mfma(const u16* __restrict__ xn,
        const u16* __restrict__ wc,
        u16* __restrict__ qb, u16* __restrict__ kb, u16* __restrict__ vt) {
    const int mb   = blockIdx.x >> 1;
    const int half = blockIdx.x & 1;
    const int row0 = mb * 32;
    const int t = threadIdx.x;
    const int w = t >> 6, lane = t & 63;
    const int quad = lane >> 4, r15 = lane & 15;
    const int mt = w >> 1, cgrp = w & 1;
    __shared__ u16 Xs[2][32 * 128];   // 2 x 8 KB
    __shared__ u16 Ws[2][96 * 128];   // 2 x 24 KB
    f32x4 acc[3] = {};
    const int xrow = mt * 16 + r15;

    // staging helper indices (constant per thread)
    const int sx_row = t >> 3, sx_ch = t & 7;

    // ---- prologue: stage chunk 0 into buffer 0 ----
    {
        #pragma unroll
        for (int hf = 0; hf < 2; ++hf) {
            const uint4 d = *(const uint4*)(xn + (size_t)(row0 + sx_row) * E
                                            + 0 * 128 + hf * 64 + sx_ch * 8);
            *(uint4*)&Xs[0][sx_row * 128 + hf * 64 + (sx_ch ^ (sx_row & 7)) * 8] = d;
        }
        #pragma unroll
        for (int i = 0; i < 6; ++i) {
            const int idx = i * 256 + t;
            const int wl = idx >> 4, ch16 = idx & 15;
            const int hf = ch16 >> 3, ch = ch16 & 7;
            const uint4 d = *(const uint4*)(wc + (size_t)(half * 96 + wl) * E
                                            + 0 * 128 + hf * 64 + ch * 8);
            *(uint4*)&Ws[0][wl * 128 + hf * 64 + (ch ^ (wl & 7)) * 8] = d;
        }
    }
    __syncthreads();

    for (int kc8 = 0; kc8 < 8; ++kc8) {
        const int cur = kc8 & 1;
        // ---- issue stage of chunk kc8+1 into the other buffer (overlaps compute) ----
        if (kc8 < 7) {
            const int nxt = cur ^ 1, kn = kc8 + 1;
            #pragma unroll
            for (int hf = 0; hf < 2; ++hf) {
                const uint4 d = *(const uint4*)(xn + (size_t)(row0 + sx_row) * E
                                                + kn * 128 + hf * 64 + sx_ch * 8);
                *(uint4*)&Xs[nxt][sx_row * 128 + hf * 64 + (sx_ch ^ (sx_row & 7)) * 8] = d;
            }
            #pragma unroll
            for (int i = 0; i < 6; ++i) {
                const int idx = i * 256 + t;
                const int wl = idx >> 4, ch16 = idx & 15;
                const int hf = ch16 >> 3, ch = ch16 & 7;
                const uint4 d = *(const uint4*)(wc + (size_t)(half * 96 + wl) * E
                                                + kn * 128 + hf * 64 + ch * 8);
                *(uint4*)&Ws[nxt][wl * 128 + hf * 64 + (ch ^ (wl & 7)) * 8] = d;
            }
        }
        // ---- compute on current buffer ----
        #pragma unroll
        for (int kk = 0; kk < 4; ++kk) {
            const int hf = kk >> 1, q4 = (kk & 1) * 4 + quad;
            const bf16x8 af = *(const bf16x8*)&Xs[cur][xrow * 128 + hf * 64 + (q4 ^ (xrow & 7)) * 8];
            #pragma unroll
            for (int j = 0; j < 3; ++j) {
                const int wl = (cgrp * 3 + j) * 16 + r15;
                const bf16x8 bfr = *(const bf16x8*)&Ws[cur][wl * 128 + hf * 64 + (q4 ^ (wl & 7)) * 8];
                acc[j] = __builtin_amdgcn_mfma_f32_16x16x32_bf16(af, bfr, acc[j], 0, 0, 0);
            }
        }
        __syncthreads();   // next-buffer writes done; current buffer free for overwrite
    }
    const int b    = row0 >> 11;
    const int key0 = row0 & 2047;
    #pragma unroll
    for (int j = 0; j < 3; ++j) {
        const int cg  = half * 96 + cgrp * 48 + j * 16 + r15;
        const int sel = cg >> 6;
        const int col = cg & 63;
        if (sel < 2) {
            u16* base = (sel == 0) ? qb : kb;
            #pragma unroll
            for (int r = 0; r < 4; ++r) {
                const size_t row = (size_t)row0 + mt * 16 + quad * 4 + r;
                base[row * HH + col] = f2bf(acc[j][r]);
            }
        } else {
            ushort4 pk;
            pk.x = f2bf(acc[j][0]); pk.y = f2bf(acc[j][1]);
            pk.z = f2bf(acc[j][2]); pk.w = f2bf(acc[j][3]);
            *(ushort4*)(vt + (size_t)b * HH * SS + (size_t)col * SS
                           + key0 + mt * 16 + quad * 4) = pk;
        }
    }
}

// ---------- Kernel 3: split-K causal flash attention — PAIRED query tiles, HEAVY-FIRST ----------
// Block = (b, a-group, rp: tile pair, c: 256-key chunk). The flat pair-slot is
// REVERSED (s2 = 71 - raw) so a=7 blocks (4 tiles staged, 8 q-strips = ~4x the work
// of a=0) dispatch FIRST; the light direct-write blocks fill the tail. Slot layout,
// math, and all inner code unchanged from the proven 118.6 version.
__global__ __launch_bounds__(256) void attn_partial(const u16* __restrict__ qb,
        const u16* __restrict__ kb, const u16* __restrict__ vt,
        u16* __restrict__ po, float* __restrict__ pl,
        float* __restrict__ out) {
    const int bid = blockIdx.x;                 // BB * 72
    const int b   = bid / 72;
    const int s2  = 71 - (bid - b * 72);        // heavy-first: reverse pair-slot order
    int a = (int)((sqrtf(4.0f * s2 + 1.0f) - 1.0f) * 0.5f);
    while ((a + 1) * (a + 2) <= s2) ++a;        // fixup (fp edge safety)
    while (a * (a + 1) > s2) --a;
    const int rem = s2 - a * (a + 1);
    const int rp  = rem / (a + 1);
    const int c   = rem - rp * (a + 1);
    const int qt0 = 4 * a + 2 * rp;             // pair (qt0, qt0+1)
    const int nc  = a + 1;
    const int t = threadIdx.x;
    const int w = t >> 6, lane = t & 63;
    const int quad = lane >> 4, r15 = lane & 15;

    __shared__ u16 Ks[4 * 64 * 64];   // 32 KB: [tile][key][h], XOR-swizzled chunks
    __shared__ u16 VT[4 * 64 * 64];   // 32 KB: [tile][h][key], XOR-swizzled chunks
    __shared__ u16 Ps[64 * 64];       // 8 KB:  [qrow][key], per-wave strips (reused per qi)

    // Q A-frags for both tiles of the pair
    bf16x8 qf0[2], qf1[2];
    #pragma unroll
    for (int qi = 0; qi < 2; ++qi) {
        const size_t qrow = ((size_t)b * SS + (qt0 + qi) * 64 + w * 16 + r15) * HH;
        qf0[qi] = *(const bf16x8*)(qb + qrow + quad * 8);
        qf1[qi] = *(const bf16x8*)(qb + qrow + 32 + quad * 8);
    }

    // tiles to stage: all 4 for interior chunks; 2rp+2 for the diagonal chunk (c==a)
    const int ntmax = (c < a) ? 4 : (2 * rp + 2);

    {   // ---- stage ALL needed tiles in one burst ----
        const int row = t >> 2, ch0 = (t & 3) * 2;
        for (int tl = 0; tl < ntmax; ++tl) {
            const int kt = (c * 4 + tl) << 6;
            const uint4* srcK = (const uint4*)(kb + ((size_t)b * SS + kt + row) * HH + ch0 * 8);
            const uint4 k0 = srcK[0], k1 = srcK[1];
            *(uint4*)&Ks[tl * 4096 + row * 64 + ((ch0    ) ^ (row & 7)) * 8] = k0;
            *(uint4*)&Ks[tl * 4096 + row * 64 + ((ch0 + 1) ^ (row & 7)) * 8] = k1;
            const uint4* srcV = (const uint4*)(vt + (size_t)b * HH * SS + (size_t)row * SS
                                               + kt + ch0 * 8);
            const uint4 v0 = srcV[0], v1 = srcV[1];
            *(uint4*)&VT[tl * 4096 + row * 64 + ((ch0    ) ^ (row & 7)) * 8] = v0;
            *(uint4*)&VT[tl * 4096 + row * 64 + ((ch0 + 1) ^ (row & 7)) * 8] = v1;
        }
    }
    __syncthreads();   // the ONLY block-wide barrier

    f32x4 o[2][4] = {};
    float l_[2][4] = {};

    for (int tl = 0; tl < ntmax; ++tl) {
        const int tile = c * 4 + tl;
        const u16* KsT = &Ks[tl * 4096];
        const u16* VTT = &VT[tl * 4096];

        // K/V fragments: loaded ONCE per tile, reused by both q-strips
        bf16x8 kf0[4], kf1[4], vf0[4], vf1[4];
        #pragma unroll
        for (int nt = 0; nt < 4; ++nt) {
            const int krow = nt * 16 + r15;
            kf0[nt] = *(const bf16x8*)&KsT[krow * 64 + ((    quad) ^ (krow & 7)) * 8];
            kf1[nt] = *(const bf16x8*)&KsT[krow * 64 + ((4 + quad) ^ (krow & 7)) * 8];
            vf0[nt] = *(const bf16x8*)&VTT[krow * 64 + ((    quad) ^ (krow & 7)) * 8];
            vf1[nt] = *(const bf16x8*)&VTT[krow * 64 + ((4 + quad) ^ (krow & 7)) * 8];
        }

        #pragma unroll
        for (int qi = 0; qi < 2; ++qi) {
            const int qt_i = qt0 + qi;
            if (tile > qt_i) continue;       // only fires: c==a, qi==0, tl==2rp+1

            // S strip = Q K^T (16 x 64)
            f32x4 s4[4] = {};
            #pragma unroll
            for (int nt = 0; nt < 4; ++nt) {
                s4[nt] = __builtin_amdgcn_mfma_f32_16x16x32_bf16(qf0[qi], kf0[nt], s4[nt], 0, 0, 0);
                s4[nt] = __builtin_amdgcn_mfma_f32_16x16x32_bf16(qf1[qi], kf1[nt], s4[nt], 0, 0, 0);
            }
            if (tile == qt_i) {   // diagonal tile: mask key > query
                #pragma unroll
                for (int nt = 0; nt < 4; ++nt)
                    #pragma unroll
                    for (int r = 0; r < 4; ++r)
                        if (nt * 16 + r15 > w * 16 + quad * 4 + r) s4[nt][r] = -INFINITY;
            }

            // un-shifted softmax: p = exp2(s). Row sums deferred (per-lane).
            float p[4][4];
            #pragma unroll
            for (int r = 0; r < 4; ++r) {
                #pragma unroll
                for (int nt = 0; nt < 4; ++nt)
                    p[nt][r] = __builtin_amdgcn_exp2f(s4[nt][r]);
                l_[qi][r] += (p[0][r] + p[1][r]) + (p[2][r] + p[3][r]);
            }

            // P strip -> LDS (per-wave strip, reused across qi; in-wave ordering)
            #pragma unroll
            for (int nt = 0; nt < 4; ++nt)
                #pragma unroll
                for (int r = 0; r < 4; ++r) {
                    const int prow = w * 16 + quad * 4 + r;
                    const int col  = nt * 16 + r15;
                    Ps[prow * 64 + (((col >> 3) ^ (prow & 7)) * 8) + (col & 7)] = f2bf(p[nt][r]);
                }
            const int arow = w * 16 + r15;
            const bf16x8 pf0 = *(const bf16x8*)&Ps[arow * 64 + ((    quad) ^ (arow & 7)) * 8];
            const bf16x8 pf1 = *(const bf16x8*)&Ps[arow * 64 + ((4 + quad) ^ (arow & 7)) * 8];

            // O strip += P V
            #pragma unroll
            for (int ht = 0; ht < 4; ++ht) {
                o[qi][ht] = __builtin_amdgcn_mfma_f32_16x16x32_bf16(pf0, vf0[ht], o[qi][ht], 0, 0, 0);
                o[qi][ht] = __builtin_amdgcn_mfma_f32_16x16x32_bf16(pf1, vf1[ht], o[qi][ht], 0, 0, 0);
            }
        }
    }

    // one row-sum reduction per block per tile-pair
    #pragma unroll
    for (int qi = 0; qi < 2; ++qi)
        #pragma unroll
        for (int r = 0; r < 4; ++r) {
            l_[qi][r] += __shfl_xor(l_[qi][r], 1); l_[qi][r] += __shfl_xor(l_[qi][r], 2);
            l_[qi][r] += __shfl_xor(l_[qi][r], 4); l_[qi][r] += __shfl_xor(l_[qi][r], 8);
        }

    #pragma unroll
    for (int qi = 0; qi < 2; ++qi) {
        const int qt_i = qt0 + qi;
        if (nc == 1) {   // a==0: pair saw all keys -> write out directly
            #pragma unroll
            for (int r = 0; r < 4; ++r) {
                const float inv = 1.0f / l_[qi][r];
                const size_t orow = ((size_t)b * SS + qt_i * 64 + w * 16 + quad * 4 + r) * HH;
                #pragma unroll
                for (int ht = 0; ht < 4; ++ht)
                    out[orow + ht * 16 + r15] = o[qi][ht][r] * inv;
            }
        } else {
            const int slot = b * NSLOT + 2 * a * (a + 1) + (2 * rp + qi) * (a + 1) + c;
            #pragma unroll
            for (int r = 0; r < 4; ++r) {
                const int q = w * 16 + quad * 4 + r;
                #pragma unroll
                for (int ht = 0; ht < 4; ++ht)
                    po[(size_t)slot * 4096 + q * 64 + ht * 16 + r15] = f2bf(o[qi][ht][r]);
                if (r15 == 0) pl[slot * 64 + q] = l_[qi][r];
            }
        }
    }
}

// ---------- Kernel 4: split-K reduce — plain sums (po is bf16), qt>=4 only, HEAVY-FIRST ----------
__global__ __launch_bounds__(256) void attn_reduce(const u16* __restrict__ po,
        const float* __restrict__ pl, float* __restrict__ out) {
    const int bid = blockIdx.x;            // BB*28*4 = 448 (qt 4..31 only)
    const int b = bid / 112, rem = bid - b * 112;
    const int qt = 31 - (rem >> 2);        // heavy-first: qt=31 (nc=8) dispatched first
    const int qq = rem & 3;
    const int a = qt >> 2, r_ = qt & 3;
    const int nc = a + 1;
    const int sbase = b * NSLOT + 2 * a * (a + 1) + r_ * (a + 1);
    const int t = threadIdx.x;
    const int h = t & 63, qr = t >> 6;
    #pragma unroll
    for (int i = 0; i < 4; ++i) {
        const int q = qq * 16 + qr * 4 + i;   // query within 64-tile
        float osum = 0.f, lsum = 0.f;
        // fixed-trip predicated unroll (nc is block-uniform, 2..8): ILP on the chunk loads
        #pragma unroll
        for (int cidx = 0; cidx < 8; ++cidx) {
            if (cidx < nc) {
                osum += bf2f(po[(size_t)(sbase + cidx) * 4096 + q * 64 + h]);
                lsum += pl[(sbase + cidx) * 64 + q];
            }
        }
        out[((size_t)b * SS + (qt << 6) + q) * HH + h] = osum / lsum;
    }
}

// ---------- launch ----------
extern "C" void kernel_launch(void* const* d_in, const int* in_sizes, int n_in,
                              void* d_out, int out_size, void* d_ws, size_t ws_size,
                              hipStream_t stream) {
    const float* x     = (const float*)d_in[0];
    const float* gamma = (const float*)d_in[1];
    const float* beta  = (const float*)d_in[2];
    const float* Wq    = (const float*)d_in[3];
    const float* Wk    = (const float*)d_in[4];
    const float* Wv    = (const float*)d_in[5];
    float* out = (float*)d_out;

    // ws layout: xn 16.78MB | wc 384KB | qb/kb/vt 1MB each | po 4.72MB (bf16) | pl 144KB
    char* p = (char*)d_ws;
    u16*   xn   = (u16*)p;                         p += (size_t)BS * E * 2;
    u16*   wc   = (u16*)p;                         p += 393216;
    u16*   qb   = (u16*)p;                         p += (size_t)BS * HH * 2;
    u16*   kb   = (u16*)p;                         p += (size_t)BS * HH * 2;
    u16*   vt   = (u16*)p;                         p += (size_t)BS * HH * 2;
    u16*   po   = (u16*)p;                         p += (size_t)BB * NSLOT * 4096 * 2;
    float* pl   = (float*)p;

    ln_wcast    <<<2048 + 192,  256, 0, stream>>>(x, gamma, beta, Wq, Wk, Wv, xn, wc);
    qkv_mfma    <<<BS / 16,     256, 0, stream>>>(xn, wc, qb, kb, vt);
    attn_partial<<<BB * 72,     256, 0, stream>>>(qb, kb, vt, po, pl, out);
    attn_reduce <<<BB * 112,    256, 0, stream>>>(po, pl, out);
}